// Round 9
// baseline (312.593 us; speedup 1.0000x reference)
//
#include <hip/hip_runtime.h>
#include <hip/hip_cooperative_groups.h>

namespace cg = cooperative_groups;

#define C2 0.17677669529663687f  // 1/(4*sqrt(2))

typedef __attribute__((ext_vector_type(8))) short short8;
typedef __attribute__((ext_vector_type(8))) unsigned short ushort8;
typedef __attribute__((ext_vector_type(4))) float f32x4;

__device__ __forceinline__ unsigned short f2bf(float x) {
    union { float f; unsigned u; } v; v.f = x;
    unsigned r = v.u + 0x7fffu + ((v.u >> 16) & 1u);
    return (unsigned short)(r >> 16);
}
__device__ __forceinline__ float bf2f(unsigned short u) {
    union { unsigned u; float f; } v; v.u = ((unsigned)u) << 16;
    return v.f;
}

// LDS union: max member 62,592 B (< 64 KB static limit, < 160 KB/CU -> >=1 block/CU,
// so a 256-block cooperative launch is always co-resident)
struct S1 { unsigned short Al[2][2][64][40]; unsigned short Bl[2][2][64][40]; float red[64][65]; };
struct S2 { float Kc[64][17]; unsigned short Pk[320][72]; unsigned short Vt[80][72]; };
struct S4 { float Qc[64][17]; float Kc[64][17]; unsigned short Pq[64][200]; unsigned short Sv[64][200];
            float zl[288]; float dpart[6][64]; };
union SMem { S1 s1; S2 s2; S4 s4; };

// ---------------- in-block split-K MFMA GEMM (R8-verified body; LDS from union) ----------------
__device__ __forceinline__ void gemm_body(
    SMem& sm, const float* __restrict__ A, const float* __restrict__ W,
    float* __restrict__ out, int row0, int n0, int outcol0, int ldw, int outld)
{
    const int tid = threadIdx.x;
    const int g = tid >> 8;
    const int t = tid & 255;
    const int lane = t & 63, wave4 = t >> 6;
    const int wm = wave4 & 1, wn = wave4 >> 1;
    const int quad = lane >> 4, lr = lane & 15;
    const int k0base = g * 384;

    f32x4 acc[2][2] = {{{0.f,0.f,0.f,0.f},{0.f,0.f,0.f,0.f}},
                       {{0.f,0.f,0.f,0.f},{0.f,0.f,0.f,0.f}}};

    float4 ra[2], rb[2];
    #pragma unroll
    for (int l = 0; l < 2; ++l) {
        int idx = t + l * 256;
        ra[l] = *(const float4*)&A[(size_t)(row0 + (idx >> 3)) * 768 + k0base + (idx & 7) * 4];
        rb[l] = *(const float4*)&W[(size_t)(k0base + (idx >> 4)) * ldw + n0 + (idx & 15) * 4];
    }
    #pragma unroll
    for (int l = 0; l < 2; ++l) {
        int idx = t + l * 256;
        *(ushort4*)&sm.s1.Al[g][0][idx >> 3][(idx & 7) * 4] =
            make_ushort4(f2bf(ra[l].x), f2bf(ra[l].y), f2bf(ra[l].z), f2bf(ra[l].w));
        int kr = idx >> 4, nq = (idx & 15) * 4;
        int col = (((kr >> 3) ^ ((idx & 15) >> 2)) << 3) | (kr & 7);
        sm.s1.Bl[g][0][nq + 0][col] = f2bf(rb[l].x);
        sm.s1.Bl[g][0][nq + 1][col] = f2bf(rb[l].y);
        sm.s1.Bl[g][0][nq + 2][col] = f2bf(rb[l].z);
        sm.s1.Bl[g][0][nq + 3][col] = f2bf(rb[l].w);
    }
    __syncthreads();

    const int ITER = 12;
    #pragma unroll
    for (int i = 0; i < ITER; ++i) {
        const int cur = i & 1, nxt = cur ^ 1;
        float4 na[2], nb[2];
        if (i + 1 < ITER) {
            int kn = k0base + (i + 1) * 32;
            #pragma unroll
            for (int l = 0; l < 2; ++l) {
                int idx = t + l * 256;
                na[l] = *(const float4*)&A[(size_t)(row0 + (idx >> 3)) * 768 + kn + (idx & 7) * 4];
                nb[l] = *(const float4*)&W[(size_t)(kn + (idx >> 4)) * ldw + n0 + (idx & 15) * 4];
            }
        }
        short8 af[2], bfr[2];
        #pragma unroll
        for (int mi = 0; mi < 2; ++mi)
            af[mi] = *(const short8*)&sm.s1.Al[g][cur][wm * 32 + mi * 16 + lr][quad << 3];
        #pragma unroll
        for (int ni = 0; ni < 2; ++ni) {
            int csw = quad ^ ((wn * 2 + ni) & 3);
            bfr[ni] = *(const short8*)&sm.s1.Bl[g][cur][wn * 32 + ni * 16 + lr][csw << 3];
        }
        #pragma unroll
        for (int mi = 0; mi < 2; ++mi)
            #pragma unroll
            for (int ni = 0; ni < 2; ++ni)
                acc[mi][ni] = __builtin_amdgcn_mfma_f32_16x16x32_bf16(af[mi], bfr[ni], acc[mi][ni], 0, 0, 0);
        if (i + 1 < ITER) {
            #pragma unroll
            for (int l = 0; l < 2; ++l) {
                int idx = t + l * 256;
                *(ushort4*)&sm.s1.Al[g][nxt][idx >> 3][(idx & 7) * 4] =
                    make_ushort4(f2bf(na[l].x), f2bf(na[l].y), f2bf(na[l].z), f2bf(na[l].w));
                int kr = idx >> 4, nq = (idx & 15) * 4;
                int col = (((kr >> 3) ^ ((idx & 15) >> 2)) << 3) | (kr & 7);
                sm.s1.Bl[g][nxt][nq + 0][col] = f2bf(nb[l].x);
                sm.s1.Bl[g][nxt][nq + 1][col] = f2bf(nb[l].y);
                sm.s1.Bl[g][nxt][nq + 2][col] = f2bf(nb[l].z);
                sm.s1.Bl[g][nxt][nq + 3][col] = f2bf(nb[l].w);
            }
        }
        __syncthreads();
    }
    if (g == 1) {
        #pragma unroll
        for (int mi = 0; mi < 2; ++mi)
            #pragma unroll
            for (int ni = 0; ni < 2; ++ni)
                #pragma unroll
                for (int r = 0; r < 4; ++r)
                    sm.s1.red[wm * 32 + mi * 16 + quad * 4 + r][wn * 32 + ni * 16 + lr] = acc[mi][ni][r];
    }
    __syncthreads();
    if (g == 0) {
        #pragma unroll
        for (int mi = 0; mi < 2; ++mi)
            #pragma unroll
            for (int ni = 0; ni < 2; ++ni)
                #pragma unroll
                for (int r = 0; r < 4; ++r) {
                    int rr = wm * 32 + mi * 16 + quad * 4 + r;
                    int cc = wn * 32 + ni * 16 + lr;
                    out[(size_t)(row0 + rr) * outld + outcol0 + cc] = acc[mi][ni][r] + sm.s1.red[rr][cc];
                }
    }
    __syncthreads();
}

// ---------------- chunk_state (8-wave split: mg = m-tiles {0,1,2}/{3,4}, ng = 4 n-groups of 5) ----------------
__device__ __forceinline__ void stage_state(
    SMem& sm, const float* __restrict__ qkv, unsigned short* __restrict__ St,
    float* __restrict__ z, int task)
{
    const int h = task >> 4, c = task & 15;
    const int tid = threadIdx.x;
    const int lane = tid & 63, wave = tid >> 6;
    const int quad = lane >> 4, lr = lane & 15;

    if (tid < 256) {
        int s = tid >> 2, f4 = (tid & 3) * 4;
        float4 kv = *(const float4*)&qkv[(size_t)(c * 64 + s) * 1152 + 192 + h * 16 + f4];
        sm.s2.Kc[s][f4 + 0] = kv.x; sm.s2.Kc[s][f4 + 1] = kv.y;
        sm.s2.Kc[s][f4 + 2] = kv.z; sm.s2.Kc[s][f4 + 3] = kv.w;
    }
    #pragma unroll
    for (int l = 0; l < 2; ++l) {
        int idx = tid + l * 512;
        int s = idx >> 4, d4 = (idx & 15) * 4;
        float4 vv = *(const float4*)&qkv[(size_t)(c * 64 + s) * 1152 + 384 + h * 64 + d4];
        sm.s2.Vt[d4 + 0][s] = f2bf(vv.x);
        sm.s2.Vt[d4 + 1][s] = f2bf(vv.y);
        sm.s2.Vt[d4 + 2][s] = f2bf(vv.z);
        sm.s2.Vt[d4 + 3][s] = f2bf(vv.w);
    }
    for (int idx = tid; idx < 1152; idx += 512) {
        int rr = 64 + idx / 72, ss = idx % 72;
        sm.s2.Vt[rr][ss] = (rr == 64 && ss < 64) ? (unsigned short)0x3F80 : (unsigned short)0;
    }
    __syncthreads();
    for (int idx = tid; idx < 2880; idx += 512) {
        int n = idx / 9, s8 = (idx % 9) * 8;
        short8 v8;
        #pragma unroll
        for (int tt = 0; tt < 8; ++tt) {
            int s = s8 + tt;
            float ph = 0.f;
            if (s < 64 && n < 273) {
                if (n == 0) ph = 1.f;
                else if (n < 17) ph = sm.s2.Kc[s][n - 1] * 0.5f;
                else { int m = n - 17; ph = sm.s2.Kc[s][m >> 4] * sm.s2.Kc[s][m & 15] * C2; }
            }
            v8[tt] = (short)f2bf(ph);
        }
        *(short8*)&sm.s2.Pk[n][s8] = v8;
    }
    __syncthreads();

    const int mg = wave & 1, ng = wave >> 1;
    const int MT = mg ? 2 : 3, mbase = mg ? 3 : 0;
    f32x4 acc[3][5];
    #pragma unroll
    for (int a = 0; a < 3; ++a)
        #pragma unroll
        for (int b = 0; b < 5; ++b) acc[a][b] = (f32x4){0.f, 0.f, 0.f, 0.f};
    #pragma unroll
    for (int ks = 0; ks < 2; ++ks) {
        short8 af[3], bfr[5];
        for (int mt = 0; mt < MT; ++mt)
            af[mt] = *(const short8*)&sm.s2.Vt[(mbase + mt) * 16 + lr][ks * 32 + quad * 8];
        #pragma unroll
        for (int nt = 0; nt < 5; ++nt)
            bfr[nt] = *(const short8*)&sm.s2.Pk[(ng * 5 + nt) * 16 + lr][ks * 32 + quad * 8];
        for (int mt = 0; mt < MT; ++mt)
            #pragma unroll
            for (int nt = 0; nt < 5; ++nt)
                acc[mt][nt] = __builtin_amdgcn_mfma_f32_16x16x32_bf16(af[mt], bfr[nt], acc[mt][nt], 0, 0, 0);
    }
    unsigned short* Sbt = St + (size_t)task * 18432;
    float* zb = z + (size_t)task * 273;
    #pragma unroll
    for (int nt = 0; nt < 5; ++nt) {
        int n = (ng * 5 + nt) * 16 + lr;
        if (n < 273) {
            for (int mt = 0; mt < MT; ++mt) {
                int mtile = mbase + mt;
                if (mtile < 4) {
                    #pragma unroll
                    for (int r = 0; r < 4; ++r)
                        Sbt[(mtile * 16 + quad * 4 + r) * 288 + n] = f2bf(acc[mt][nt][r]);
                } else if (quad == 0) {
                    zb[n] = acc[mt][nt][0];   // d==64 ones-row
                }
            }
        }
    }
}

// ---------------- chunk_out, two K-passes (Pq/Sv = 64x200), QK^T frags from fp32 LDS ----------------
__device__ __forceinline__ void stage_out(
    SMem& sm, const float* __restrict__ qkv, const unsigned short* __restrict__ St,
    const float* __restrict__ z, float* __restrict__ y, int task)
{
    const int h = task >> 4, c = task & 15;
    const int tid = threadIdx.x;
    const int lane = tid & 63, wave = tid >> 6;
    const int wm = wave & 1, wn = (wave >> 1) & 1;
    const int quad = lane >> 4, lr = lane & 15;

    if (tid < 256) {
        int s = tid >> 2, f4 = (tid & 3) * 4;
        const float* base = &qkv[(size_t)(c * 64 + s) * 1152 + h * 16];
        float4 qv = *(const float4*)&base[f4];
        float4 kv = *(const float4*)&base[192 + f4];
        sm.s4.Qc[s][f4 + 0] = qv.x; sm.s4.Qc[s][f4 + 1] = qv.y;
        sm.s4.Qc[s][f4 + 2] = qv.z; sm.s4.Qc[s][f4 + 3] = qv.w;
        sm.s4.Kc[s][f4 + 0] = kv.x; sm.s4.Kc[s][f4 + 1] = kv.y;
        sm.s4.Kc[s][f4 + 2] = kv.z; sm.s4.Kc[s][f4 + 3] = kv.w;
    }
    const float* zg = z + (size_t)task * 273;
    for (int idx = tid; idx < 288; idx += 512) sm.s4.zl[idx] = (idx < 273) ? zg[idx] : 0.f;
    __syncthreads();

    // QK^T: frags assembled from fp32 LDS (k 0..15 data, 16..31 zero)
    f32x4 accS[2][2] = {{{0.f,0.f,0.f,0.f},{0.f,0.f,0.f,0.f}},
                        {{0.f,0.f,0.f,0.f},{0.f,0.f,0.f,0.f}}};
    float dp = 0.f;
    if (wave < 4) {
        short8 afq[2], bfk[2];
        #pragma unroll
        for (int mi = 0; mi < 2; ++mi)
            #pragma unroll
            for (int j = 0; j < 8; ++j) {
                int col = quad * 8 + j;
                afq[mi][j] = (short)((col < 16) ? f2bf(sm.s4.Qc[wm * 32 + mi * 16 + lr][col]) : 0);
            }
        #pragma unroll
        for (int ni = 0; ni < 2; ++ni)
            #pragma unroll
            for (int j = 0; j < 8; ++j) {
                int col = quad * 8 + j;
                bfk[ni][j] = (short)((col < 16) ? f2bf(sm.s4.Kc[wn * 32 + ni * 16 + lr][col]) : 0);
            }
        #pragma unroll
        for (int mi = 0; mi < 2; ++mi)
            #pragma unroll
            for (int ni = 0; ni < 2; ++ni)
                accS[mi][ni] = __builtin_amdgcn_mfma_f32_16x16x32_bf16(afq[mi], bfk[ni], accS[mi][ni], 0, 0, 0);
    }

    // ---- pass 1: global cols 0..191 (phiQ x S^T) ----
    const unsigned short* Sgt = St + (size_t)task * 18432;
    #pragma unroll
    for (int l = 0; l < 3; ++l) {
        int idx = tid + l * 512;       // < 1536
        int d = idx / 24, c8 = (idx % 24) * 8;
        *(ushort8*)&sm.s4.Sv[d][c8] = *(const ushort8*)&Sgt[d * 288 + c8];
    }
    if (wave < 4) {
        float qr[16];
        #pragma unroll
        for (int f = 0; f < 16; ++f) qr[f] = sm.s4.Qc[lane][f];
        for (int l = wave * 48; l < wave * 48 + 48; ++l) {
            float ph;
            if (l == 0) ph = 1.f;
            else if (l < 17) ph = qr[l - 1] * 0.5f;
            else { int m = l - 17; ph = qr[m >> 4] * qr[m & 15] * C2; }
            sm.s4.Pq[lane][l] = f2bf(ph);
            dp += ph * sm.s4.zl[l];
        }
    }
    __syncthreads();
    f32x4 acc[2][2] = {{{0.f,0.f,0.f,0.f},{0.f,0.f,0.f,0.f}},
                       {{0.f,0.f,0.f,0.f},{0.f,0.f,0.f,0.f}}};
    if (wave < 4) {
        #pragma unroll
        for (int ks = 0; ks < 6; ++ks) {
            short8 af[2], bfr[2];
            #pragma unroll
            for (int mi = 0; mi < 2; ++mi)
                af[mi] = *(const short8*)&sm.s4.Pq[wm * 32 + mi * 16 + lr][ks * 32 + quad * 8];
            #pragma unroll
            for (int ni = 0; ni < 2; ++ni)
                bfr[ni] = *(const short8*)&sm.s4.Sv[wn * 32 + ni * 16 + lr][ks * 32 + quad * 8];
            #pragma unroll
            for (int mi = 0; mi < 2; ++mi)
                #pragma unroll
                for (int ni = 0; ni < 2; ++ni)
                    acc[mi][ni] = __builtin_amdgcn_mfma_f32_16x16x32_bf16(af[mi], bfr[ni], acc[mi][ni], 0, 0, 0);
        }
    }
    __syncthreads();

    // ---- pass 2: local cols 0..80 = phi 192..272 | 81..95 zero | 96..159 = scores/V ----
    for (int idx = tid; idx < 640; idx += 512) {
        int d = idx / 10, c8 = (idx % 10) * 8;
        *(ushort8*)&sm.s4.Sv[d][c8] = *(const ushort8*)&Sgt[d * 288 + 192 + c8];
    }
    if (tid < 64) sm.s4.Sv[tid][80] = Sgt[tid * 288 + 272];
    for (int idx = tid; idx < 960; idx += 512) {
        int d = idx / 15, n = 81 + idx % 15;
        sm.s4.Sv[d][n] = 0;
    }
    #pragma unroll
    for (int l = 0; l < 2; ++l) {
        int idx = tid + l * 512;
        int s = idx >> 4, d4 = (idx & 15) * 4;
        float4 vv = *(const float4*)&qkv[(size_t)(c * 64 + s) * 1152 + 384 + h * 64 + d4];
        sm.s4.Sv[d4 + 0][96 + s] = f2bf(vv.x);
        sm.s4.Sv[d4 + 1][96 + s] = f2bf(vv.y);
        sm.s4.Sv[d4 + 2][96 + s] = f2bf(vv.z);
        sm.s4.Sv[d4 + 3][96 + s] = f2bf(vv.w);
    }
    if (wave < 4) {
        float qr[16];
        #pragma unroll
        for (int f = 0; f < 16; ++f) qr[f] = sm.s4.Qc[lane][f];
        for (int l = wave * 24; l < wave * 24 + 24; ++l) {
            float ph = 0.f;
            if (l < 81) {
                int n = 192 + l, m = n - 17;
                ph = qr[m >> 4] * qr[m & 15] * C2;
                dp += ph * sm.s4.zl[n];
            }
            sm.s4.Pq[lane][l] = f2bf(ph);
        }
        sm.s4.dpart[wave][lane] = dp;
        #pragma unroll
        for (int mi = 0; mi < 2; ++mi) {
            float rs[4] = {0.f, 0.f, 0.f, 0.f};
            #pragma unroll
            for (int ni = 0; ni < 2; ++ni)
                #pragma unroll
                for (int r = 0; r < 4; ++r) {
                    int i = wm * 32 + mi * 16 + quad * 4 + r;
                    int j = wn * 32 + ni * 16 + lr;
                    float u = accS[mi][ni][r];
                    float sc = (j <= i) ? (1.f + 0.25f * u + u * u * (1.f / 32.f)) : 0.f;
                    rs[r] += sc;
                    sm.s4.Pq[i][96 + j] = f2bf(sc);
                }
            #pragma unroll
            for (int r = 0; r < 4; ++r) {
                float v = rs[r];
                v += __shfl_xor(v, 1);
                v += __shfl_xor(v, 2);
                v += __shfl_xor(v, 4);
                v += __shfl_xor(v, 8);
                if (lr == 0) sm.s4.dpart[4 + wn][wm * 32 + mi * 16 + quad * 4 + r] = v;
            }
        }
    }
    __syncthreads();
    if (wave < 4) {
        #pragma unroll
        for (int ks = 0; ks < 5; ++ks) {
            short8 af[2], bfr[2];
            #pragma unroll
            for (int mi = 0; mi < 2; ++mi)
                af[mi] = *(const short8*)&sm.s4.Pq[wm * 32 + mi * 16 + lr][ks * 32 + quad * 8];
            #pragma unroll
            for (int ni = 0; ni < 2; ++ni)
                bfr[ni] = *(const short8*)&sm.s4.Sv[wn * 32 + ni * 16 + lr][ks * 32 + quad * 8];
            #pragma unroll
            for (int mi = 0; mi < 2; ++mi)
                #pragma unroll
                for (int ni = 0; ni < 2; ++ni)
                    acc[mi][ni] = __builtin_amdgcn_mfma_f32_16x16x32_bf16(af[mi], bfr[ni], acc[mi][ni], 0, 0, 0);
        }
        #pragma unroll
        for (int mi = 0; mi < 2; ++mi)
            #pragma unroll
            for (int r = 0; r < 4; ++r) {
                int i = wm * 32 + mi * 16 + quad * 4 + r;
                float den = sm.s4.dpart[0][i] + sm.s4.dpart[1][i] + sm.s4.dpart[2][i] +
                            sm.s4.dpart[3][i] + sm.s4.dpart[4][i] + sm.s4.dpart[5][i] + 1e-12f;
                float rden = 1.f / den;
                #pragma unroll
                for (int ni = 0; ni < 2; ++ni)
                    y[(size_t)(c * 64 + i) * 768 + h * 64 + wn * 32 + ni * 16 + lr] = acc[mi][ni][r] * rden;
            }
    }
    __syncthreads();
}

// ---------------- the cooperative mega-kernel ----------------
__global__ __launch_bounds__(512) void mega_k(
    const float* __restrict__ hs, const float* __restrict__ Wq, const float* __restrict__ Wk,
    const float* __restrict__ Wv, const float* __restrict__ Wo,
    float* __restrict__ out, float* __restrict__ ws)
{
    __shared__ SMem sm;
    cg::grid_group grid = cg::this_grid();
    float* qkv = ws;                                        // 1024*1152 fp32
    float* yb  = ws + 1179648;                              // 1024*768 fp32
    unsigned short* St = (unsigned short*)(ws + 1966080);   // 192 x 64 x 288 bf16
    float* zb  = ws + 5320704;                              // 192 x 273 fp32
    const int bid = blockIdx.x;

    // stage 1: qkv GEMM, 288 tiles
    for (int task = bid; task < 288; task += 256) {
        int nt = task % 18, mt = task / 18;
        const float* W; int ldw, n0;
        if (nt < 3)      { W = Wq; ldw = 192; n0 = nt * 64; }
        else if (nt < 6) { W = Wk; ldw = 192; n0 = (nt - 3) * 64; }
        else             { W = Wv; ldw = 768; n0 = (nt - 6) * 64; }
        gemm_body(sm, hs, W, qkv, mt * 64, n0, nt * 64, ldw, 1152);
    }
    grid.sync();

    // stage 2: chunk states
    if (bid < 192) stage_state(sm, qkv, St, zb, bid);
    grid.sync();

    // stage 3: exclusive prefix over 16 chunks
    {
        const int NS = 12 * 64 * 273;           // 209,664
        const int total = NS + 12 * 273;        // 212,940
        for (int e = bid * 512 + threadIdx.x; e < total; e += 131072) {
            if (e < NS) {
                int hh = e / (64 * 273), rem = e % (64 * 273);
                int d = rem / 273, n = rem % 273;
                unsigned short* p = St + (size_t)hh * 16 * 18432 + d * 288 + n;
                float run = 0.f;
                #pragma unroll
                for (int cc = 0; cc < 16; ++cc) {
                    float v = bf2f(p[cc * 18432]);
                    p[cc * 18432] = f2bf(run);
                    run += v;
                }
            } else {
                int e2 = e - NS, hh = e2 / 273, n = e2 % 273;
                float* p = zb + (size_t)hh * 16 * 273 + n;
                float run = 0.f;
                #pragma unroll
                for (int cc = 0; cc < 16; ++cc) { float v = p[cc * 273]; p[cc * 273] = run; run += v; }
            }
        }
    }
    grid.sync();

    // stage 4: chunk outputs
    if (bid < 192) stage_out(sm, qkv, St, zb, yb, bid);
    grid.sync();

    // stage 5: Wo GEMM, 192 tiles
    if (bid < 192) {
        int nt = bid % 12, mt = bid / 12;
        gemm_body(sm, yb, Wo, out, mt * 64, nt * 64, nt * 64, 768, 768);
    }
}

extern "C" void kernel_launch(void* const* d_in, const int* in_sizes, int n_in,
                              void* d_out, int out_size, void* d_ws, size_t ws_size,
                              hipStream_t stream) {
    const float* hs = (const float*)d_in[0];
    const float* Wq = (const float*)d_in[1];
    const float* Wk = (const float*)d_in[2];
    const float* Wv = (const float*)d_in[3];
    const float* Wo = (const float*)d_in[4];
    float* out = (float*)d_out;
    float* ws  = (float*)d_ws;

    void* args[] = { (void*)&hs, (void*)&Wq, (void*)&Wk, (void*)&Wv, (void*)&Wo,
                     (void*)&out, (void*)&ws };
    hipLaunchCooperativeKernel((const void*)mega_k, dim3(256), dim3(512), args, 0, stream);
}

// Round 10
// 168.206 us; speedup vs baseline: 1.8584x; 1.8584x over previous
//
#include <hip/hip_runtime.h>

#define C2 0.17677669529663687f  // 1/(4*sqrt(2))

typedef __attribute__((ext_vector_type(8))) short short8;
typedef __attribute__((ext_vector_type(8))) unsigned short ushort8;
typedef __attribute__((ext_vector_type(4))) float f32x4;

// fp32 -> bf16 round-to-nearest-even
__device__ __forceinline__ unsigned short f2bf(float x) {
    union { float f; unsigned u; } v; v.f = x;
    unsigned r = v.u + 0x7fffu + ((v.u >> 16) & 1u);
    return (unsigned short)(r >> 16);
}
__device__ __forceinline__ float bf2f(unsigned short u) {
    union { unsigned u; float f; } v; v.u = ((unsigned)u) << 16;
    return v.f;
}

// ---------------- in-block split-K MFMA GEMM, 32x64 tile ----------------
// 512 threads: K-groups g=0/1 (384 each), 4 waves/group, wave tile 32x16 (2 MFMA/step).
// Register-prefetch double-buffered LDS, one barrier per K-step; g1 dumps partial to LDS,
// g0 adds + stores. Grid doubles vs 64-row tiles (R6->R7 showed GEMMs are block-starved).
__device__ __forceinline__ void gemm_inblk_splitk(
    const float* __restrict__ A, const float* __restrict__ W,
    float* __restrict__ out, int row0, int n0, int outcol0, int ldw, int outld)
{
    __shared__ unsigned short Al[2][2][32][40];   // [group][buf][m][k]
    __shared__ unsigned short Bl[2][2][64][40];   // [group][buf][n][k-swizzled]
    __shared__ float red[32][65];
    const int tid = threadIdx.x;
    const int g = tid >> 8;
    const int t = tid & 255;
    const int lane = t & 63, w4 = t >> 6;          // wave within group: n-tile
    const int quad = lane >> 4, lr = lane & 15;
    const int k0base = g * 384;

    f32x4 acc[2] = {{0.f,0.f,0.f,0.f},{0.f,0.f,0.f,0.f}};

    float4 ra, rb[2];
    {
        ra = *(const float4*)&A[(size_t)(row0 + (t >> 3)) * 768 + k0base + (t & 7) * 4];
        #pragma unroll
        for (int l = 0; l < 2; ++l) {
            int idy = t + l * 256;
            rb[l] = *(const float4*)&W[(size_t)(k0base + (idy >> 4)) * ldw + n0 + (idy & 15) * 4];
        }
    }
    {
        *(ushort4*)&Al[g][0][t >> 3][(t & 7) * 4] =
            make_ushort4(f2bf(ra.x), f2bf(ra.y), f2bf(ra.z), f2bf(ra.w));
        #pragma unroll
        for (int l = 0; l < 2; ++l) {
            int idy = t + l * 256;
            int kr = idy >> 4, nq = (idy & 15) * 4;
            int col = (((kr >> 3) ^ ((idy & 15) >> 2)) << 3) | (kr & 7);
            Bl[g][0][nq + 0][col] = f2bf(rb[l].x);
            Bl[g][0][nq + 1][col] = f2bf(rb[l].y);
            Bl[g][0][nq + 2][col] = f2bf(rb[l].z);
            Bl[g][0][nq + 3][col] = f2bf(rb[l].w);
        }
    }
    __syncthreads();

    const int ITER = 12;   // 384 / 32
    #pragma unroll
    for (int i = 0; i < ITER; ++i) {
        const int cur = i & 1, nxt = cur ^ 1;
        float4 na, nb[2];
        if (i + 1 < ITER) {
            int kn = k0base + (i + 1) * 32;
            na = *(const float4*)&A[(size_t)(row0 + (t >> 3)) * 768 + kn + (t & 7) * 4];
            #pragma unroll
            for (int l = 0; l < 2; ++l) {
                int idy = t + l * 256;
                nb[l] = *(const float4*)&W[(size_t)(kn + (idy >> 4)) * ldw + n0 + (idy & 15) * 4];
            }
        }
        short8 af[2], bfr;
        af[0] = *(const short8*)&Al[g][cur][lr][quad << 3];
        af[1] = *(const short8*)&Al[g][cur][16 + lr][quad << 3];
        {
            int csw = quad ^ (w4 & 3);
            bfr = *(const short8*)&Bl[g][cur][w4 * 16 + lr][csw << 3];
        }
        acc[0] = __builtin_amdgcn_mfma_f32_16x16x32_bf16(af[0], bfr, acc[0], 0, 0, 0);
        acc[1] = __builtin_amdgcn_mfma_f32_16x16x32_bf16(af[1], bfr, acc[1], 0, 0, 0);
        if (i + 1 < ITER) {
            *(ushort4*)&Al[g][nxt][t >> 3][(t & 7) * 4] =
                make_ushort4(f2bf(na.x), f2bf(na.y), f2bf(na.z), f2bf(na.w));
            #pragma unroll
            for (int l = 0; l < 2; ++l) {
                int idy = t + l * 256;
                int kr = idy >> 4, nq = (idy & 15) * 4;
                int col = (((kr >> 3) ^ ((idy & 15) >> 2)) << 3) | (kr & 7);
                Bl[g][nxt][nq + 0][col] = f2bf(nb[l].x);
                Bl[g][nxt][nq + 1][col] = f2bf(nb[l].y);
                Bl[g][nxt][nq + 2][col] = f2bf(nb[l].z);
                Bl[g][nxt][nq + 3][col] = f2bf(nb[l].w);
            }
        }
        __syncthreads();
    }
    if (g == 1) {
        #pragma unroll
        for (int mi = 0; mi < 2; ++mi)
            #pragma unroll
            for (int r = 0; r < 4; ++r)
                red[mi * 16 + quad * 4 + r][w4 * 16 + lr] = acc[mi][r];
    }
    __syncthreads();
    if (g == 0) {
        #pragma unroll
        for (int mi = 0; mi < 2; ++mi)
            #pragma unroll
            for (int r = 0; r < 4; ++r) {
                int rr = mi * 16 + quad * 4 + r;
                out[(size_t)(row0 + rr) * outld + outcol0 + w4 * 16 + lr] =
                    acc[mi][r] + red[rr][w4 * 16 + lr];
            }
    }
}

// qkv: hidden(1024x768) @ [Wq|Wk|Wv] -> qkv(1024x1152). grid (18,32) x 512
__global__ __launch_bounds__(512) void gemm_qkv_mfma(
    const float* __restrict__ H, const float* __restrict__ Wq,
    const float* __restrict__ Wk, const float* __restrict__ Wv,
    float* __restrict__ out)
{
    const int nt = blockIdx.x, mt = blockIdx.y;
    const float* W; int ldw, n0;
    if (nt < 3)      { W = Wq; ldw = 192; n0 = nt * 64; }
    else if (nt < 6) { W = Wk; ldw = 192; n0 = (nt - 3) * 64; }
    else             { W = Wv; ldw = 768; n0 = (nt - 6) * 64; }
    gemm_inblk_splitk(H, W, out, mt * 32, n0, nt * 64, ldw, 1152);
}

// wo: y(1024x768) @ Wo(768x768) -> out(1024x768). grid (12,32) x 512
__global__ __launch_bounds__(512) void gemm_wo_mfma(
    const float* __restrict__ Y, const float* __restrict__ Wo, float* __restrict__ out)
{
    const int nt = blockIdx.x, mt = blockIdx.y;
    gemm_inblk_splitk(Y, Wo, out, mt * 32, nt * 64, nt * 64, 768, 768);
}

// ---------------- per-chunk state via MFMA -> S_T bf16 (raw, unscanned) ----------------
// S_T[h][c][d][n] (ld=288, bf16): A = [V^T|ones] (m=80pad, row 64 = ones for z), B = phiK (n=320pad).
// grid (16, 12) x 256.
__global__ __launch_bounds__(256) void chunk_state_k(
    const float* __restrict__ qkv, unsigned short* __restrict__ St, float* __restrict__ z)
{
    const int c = blockIdx.x, h = blockIdx.y;
    __shared__ float Kc[64][17];
    __shared__ unsigned short Pk[320][72];
    __shared__ unsigned short Vt[80][72];
    const int tid = threadIdx.x;
    const int lane = tid & 63, wave = tid >> 6;
    const int quad = lane >> 4, lr = lane & 15;

    {
        int s = tid >> 2, f4 = (tid & 3) * 4;
        float4 kv = *(const float4*)&qkv[(size_t)(c * 64 + s) * 1152 + 192 + h * 16 + f4];
        Kc[s][f4 + 0] = kv.x; Kc[s][f4 + 1] = kv.y; Kc[s][f4 + 2] = kv.z; Kc[s][f4 + 3] = kv.w;
    }
    #pragma unroll
    for (int l = 0; l < 4; ++l) {
        int idx = tid + l * 256;
        int s = idx >> 4, d4 = (idx & 15) * 4;
        float4 vv = *(const float4*)&qkv[(size_t)(c * 64 + s) * 1152 + 384 + h * 64 + d4];
        Vt[d4 + 0][s] = f2bf(vv.x);
        Vt[d4 + 1][s] = f2bf(vv.y);
        Vt[d4 + 2][s] = f2bf(vv.z);
        Vt[d4 + 3][s] = f2bf(vv.w);
    }
    for (int idx = tid; idx < 16 * 72; idx += 256) {
        int rr = 64 + idx / 72, ss = idx % 72;
        Vt[rr][ss] = (rr == 64 && ss < 64) ? (unsigned short)0x3F80 : (unsigned short)0;
    }
    __syncthreads();
    for (int idx = tid; idx < 2880; idx += 256) {
        int n = idx / 9, s8 = (idx % 9) * 8;
        short8 v8;
        #pragma unroll
        for (int tt = 0; tt < 8; ++tt) {
            int s = s8 + tt;
            float ph = 0.f;
            if (s < 64 && n < 273) {
                if (n == 0) ph = 1.f;
                else if (n < 17) ph = Kc[s][n - 1] * 0.5f;
                else { int m = n - 17; ph = Kc[s][m >> 4] * Kc[s][m & 15] * C2; }
            }
            v8[tt] = (short)f2bf(ph);
        }
        *(short8*)&Pk[n][s8] = v8;
    }
    __syncthreads();

    f32x4 acc[5][5];
    #pragma unroll
    for (int a = 0; a < 5; ++a)
        #pragma unroll
        for (int b = 0; b < 5; ++b) acc[a][b] = (f32x4){0.f, 0.f, 0.f, 0.f};
    #pragma unroll
    for (int ks = 0; ks < 2; ++ks) {
        short8 af[5], bfr[5];
        #pragma unroll
        for (int mt = 0; mt < 5; ++mt)
            af[mt] = *(const short8*)&Vt[mt * 16 + lr][ks * 32 + quad * 8];
        #pragma unroll
        for (int nt = 0; nt < 5; ++nt)
            bfr[nt] = *(const short8*)&Pk[(wave * 5 + nt) * 16 + lr][ks * 32 + quad * 8];
        #pragma unroll
        for (int mt = 0; mt < 5; ++mt)
            #pragma unroll
            for (int nt = 0; nt < 5; ++nt)
                acc[mt][nt] = __builtin_amdgcn_mfma_f32_16x16x32_bf16(af[mt], bfr[nt], acc[mt][nt], 0, 0, 0);
    }
    unsigned short* Sbt = St + (size_t)(h * 16 + c) * 18432;
    float* zb = z + (size_t)(h * 16 + c) * 273;
    #pragma unroll
    for (int nt = 0; nt < 5; ++nt) {
        int n = (wave * 5 + nt) * 16 + lr;
        if (n < 273) {
            #pragma unroll
            for (int mt = 0; mt < 4; ++mt)
                #pragma unroll
                for (int r = 0; r < 4; ++r)
                    Sbt[(mt * 16 + quad * 4 + r) * 288 + n] = f2bf(acc[mt][nt][r]);
            if (quad == 0) zb[n] = acc[4][nt][0];   // d==64 ones-row -> z
        }
    }
}

// ---------------- per-chunk output; exclusive prefix over chunks FUSED (reads raw states) ----------------
// grid (16, 12) x 256
__global__ __launch_bounds__(256) void chunk_out_k(
    const float* __restrict__ qkv, const unsigned short* __restrict__ St, const float* __restrict__ z,
    float* __restrict__ y)
{
    const int c = blockIdx.x, h = blockIdx.y;
    __shared__ float Qc[64][17];
    __shared__ unsigned short Aq[64][40];
    __shared__ unsigned short Kb[64][40];
    __shared__ unsigned short Pq[64][360];
    __shared__ unsigned short Sv[64][360];
    __shared__ float zl[288];
    __shared__ float dpart[6][64];
    const int tid = threadIdx.x;
    const int lane = tid & 63, wave = tid >> 6;
    const int wm = wave & 1, wn = wave >> 1;
    const int quad = lane >> 4, lr = lane & 15;

    {
        int s = tid >> 2, f4 = (tid & 3) * 4;
        const float* base = &qkv[(size_t)(c * 64 + s) * 1152 + h * 16];
        float4 qv = *(const float4*)&base[f4];
        float4 kv = *(const float4*)&base[192 + f4];
        Qc[s][f4 + 0] = qv.x; Qc[s][f4 + 1] = qv.y; Qc[s][f4 + 2] = qv.z; Qc[s][f4 + 3] = qv.w;
        *(ushort4*)&Aq[s][f4] = make_ushort4(f2bf(qv.x), f2bf(qv.y), f2bf(qv.z), f2bf(qv.w));
        *(ushort4*)&Kb[s][f4] = make_ushort4(f2bf(kv.x), f2bf(kv.y), f2bf(kv.z), f2bf(kv.w));
        *(ushort4*)&Aq[s][16 + (tid & 3) * 4] = make_ushort4(0, 0, 0, 0);
        *(ushort4*)&Kb[s][16 + (tid & 3) * 4] = make_ushort4(0, 0, 0, 0);
    }
    #pragma unroll
    for (int l = 0; l < 4; ++l) {                    // V -> Sv cols 288..351
        int idx = tid + l * 256;
        int s = idx >> 4, d4 = (idx & 15) * 4;
        float4 vv = *(const float4*)&qkv[(size_t)(c * 64 + s) * 1152 + 384 + h * 64 + d4];
        Sv[d4 + 0][288 + s] = f2bf(vv.x);
        Sv[d4 + 1][288 + s] = f2bf(vv.y);
        Sv[d4 + 2][288 + s] = f2bf(vv.z);
        Sv[d4 + 3][288 + s] = f2bf(vv.w);
    }
    // fused exclusive prefix: Sv[d][n] = sum_{cp<c} St_raw[h][cp][d][n] (fp32 accum, bf16 store);
    // cols 273..287 forced to 0. 2304 ushort8 slices over 256 threads (coalesced).
    {
        const unsigned short* Sg0 = St + (size_t)h * 16 * 18432;
        #pragma unroll
        for (int j = 0; j < 9; ++j) {
            int idx = tid + j * 256;                 // 0..2303
            int d = idx / 36, n8 = (idx % 36) * 8;   // n8 = 0..280
            float a[8] = {0.f, 0.f, 0.f, 0.f, 0.f, 0.f, 0.f, 0.f};
            for (int cp = 0; cp < c; ++cp) {
                ushort8 v = *(const ushort8*)&Sg0[(size_t)cp * 18432 + d * 288 + n8];
                #pragma unroll
                for (int tt = 0; tt < 8; ++tt) a[tt] += bf2f(v[tt]);
            }
            unsigned short ov[8];
            #pragma unroll
            for (int tt = 0; tt < 8; ++tt)
                ov[tt] = ((n8 + tt) < 273) ? f2bf(a[tt]) : (unsigned short)0;
            *(ushort8*)&Sv[d][n8] = *(ushort8*)ov;
        }
    }
    // fused z prefix
    {
        const float* zg0 = z + (size_t)h * 16 * 273;
        for (int idx = tid; idx < 288; idx += 256) {
            float s = 0.f;
            if (idx < 273)
                for (int cp = 0; cp < c; ++cp) s += zg0[cp * 273 + idx];
            zl[idx] = s;
        }
    }
    __syncthreads();

    f32x4 accS[2][2] = {{{0.f,0.f,0.f,0.f},{0.f,0.f,0.f,0.f}},
                        {{0.f,0.f,0.f,0.f},{0.f,0.f,0.f,0.f}}};
    {
        short8 af[2], bfr[2];
        #pragma unroll
        for (int mi = 0; mi < 2; ++mi)
            af[mi] = *(const short8*)&Aq[wm * 32 + mi * 16 + lr][quad * 8];
        #pragma unroll
        for (int ni = 0; ni < 2; ++ni)
            bfr[ni] = *(const short8*)&Kb[wn * 32 + ni * 16 + lr][quad * 8];
        #pragma unroll
        for (int mi = 0; mi < 2; ++mi)
            #pragma unroll
            for (int ni = 0; ni < 2; ++ni)
                accS[mi][ni] = __builtin_amdgcn_mfma_f32_16x16x32_bf16(af[mi], bfr[ni], accS[mi][ni], 0, 0, 0);
    }

    {
        int i = lane;
        float qr[16];
        #pragma unroll
        for (int f = 0; f < 16; ++f) qr[f] = Qc[i][f];
        float dp = 0.f;
        int n0 = wave * 72;
        for (int n = n0; n < n0 + 72; ++n) {
            float ph;
            if (n == 0) ph = 1.f;
            else if (n < 17) ph = qr[n - 1] * 0.5f;
            else if (n < 273) { int m = n - 17; ph = qr[m >> 4] * qr[m & 15] * C2; }
            else ph = 0.f;
            Pq[i][n] = f2bf(ph);
            dp += ph * zl[n];
        }
        dpart[wave][i] = dp;
    }

    #pragma unroll
    for (int mi = 0; mi < 2; ++mi) {
        float rs[4] = {0.f, 0.f, 0.f, 0.f};
        #pragma unroll
        for (int ni = 0; ni < 2; ++ni)
            #pragma unroll
            for (int r = 0; r < 4; ++r) {
                int i = wm * 32 + mi * 16 + quad * 4 + r;
                int j = wn * 32 + ni * 16 + lr;
                float u = accS[mi][ni][r];
                float sc = (j <= i) ? (1.f + 0.25f * u + u * u * (1.f / 32.f)) : 0.f;
                rs[r] += sc;
                Pq[i][288 + j] = f2bf(sc);
            }
        #pragma unroll
        for (int r = 0; r < 4; ++r) {
            float v = rs[r];
            v += __shfl_xor(v, 1);
            v += __shfl_xor(v, 2);
            v += __shfl_xor(v, 4);
            v += __shfl_xor(v, 8);
            if (lr == 0) dpart[4 + wn][wm * 32 + mi * 16 + quad * 4 + r] = v;
        }
    }
    __syncthreads();

    f32x4 acc[2][2] = {{{0.f,0.f,0.f,0.f},{0.f,0.f,0.f,0.f}},
                       {{0.f,0.f,0.f,0.f},{0.f,0.f,0.f,0.f}}};
    #pragma unroll
    for (int ks = 0; ks < 11; ++ks) {
        short8 af[2], bfr[2];
        #pragma unroll
        for (int mi = 0; mi < 2; ++mi)
            af[mi] = *(const short8*)&Pq[wm * 32 + mi * 16 + lr][ks * 32 + quad * 8];
        #pragma unroll
        for (int ni = 0; ni < 2; ++ni)
            bfr[ni] = *(const short8*)&Sv[wn * 32 + ni * 16 + lr][ks * 32 + quad * 8];
        #pragma unroll
        for (int mi = 0; mi < 2; ++mi)
            #pragma unroll
            for (int ni = 0; ni < 2; ++ni)
                acc[mi][ni] = __builtin_amdgcn_mfma_f32_16x16x32_bf16(af[mi], bfr[ni], acc[mi][ni], 0, 0, 0);
    }

    #pragma unroll
    for (int mi = 0; mi < 2; ++mi)
        #pragma unroll
        for (int r = 0; r < 4; ++r) {
            int i = wm * 32 + mi * 16 + quad * 4 + r;
            float den = dpart[0][i] + dpart[1][i] + dpart[2][i] +
                        dpart[3][i] + dpart[4][i] + dpart[5][i] + 1e-12f;
            float rden = 1.f / den;
            #pragma unroll
            for (int ni = 0; ni < 2; ++ni)
                y[(size_t)(c * 64 + i) * 768 + h * 64 + wn * 32 + ni * 16 + lr] = acc[mi][ni][r] * rden;
        }
}

extern "C" void kernel_launch(void* const* d_in, const int* in_sizes, int n_in,
                              void* d_out, int out_size, void* d_ws, size_t ws_size,
                              hipStream_t stream) {
    const float* hs = (const float*)d_in[0];
    const float* Wq = (const float*)d_in[1];
    const float* Wk = (const float*)d_in[2];
    const float* Wv = (const float*)d_in[3];
    const float* Wo = (const float*)d_in[4];
    float* out = (float*)d_out;
    float* ws  = (float*)d_ws;

    float* qkv = ws;                                        // 1024*1152 fp32
    float* yb  = ws + 1179648;                              // 1024*768 fp32
    unsigned short* St = (unsigned short*)(ws + 1966080);   // 192 x 64 x 288 bf16 (raw chunk states)
    float* zb  = ws + 5320704;                              // 192 x 273 fp32 (raw chunk z)

    gemm_qkv_mfma<<<dim3(18, 32), 512, 0, stream>>>(hs, Wq, Wk, Wv, qkv);
    chunk_state_k<<<dim3(16, 12), 256, 0, stream>>>(qkv, St, zb);
    chunk_out_k  <<<dim3(16, 12), 256, 0, stream>>>(qkv, St, zb, yb);
    gemm_wo_mfma <<<dim3(12, 32), 512, 0, stream>>>(yb, Wo, out);
}

// Round 11
// 137.884 us; speedup vs baseline: 2.2671x; 1.2199x over previous
//
#include <hip/hip_runtime.h>

#define C2 0.17677669529663687f  // 1/(4*sqrt(2))

typedef __attribute__((ext_vector_type(8))) short short8;
typedef __attribute__((ext_vector_type(8))) unsigned short ushort8;
typedef __attribute__((ext_vector_type(4))) float f32x4;

// fp32 -> bf16 round-to-nearest-even
__device__ __forceinline__ unsigned short f2bf(float x) {
    union { float f; unsigned u; } v; v.f = x;
    unsigned r = v.u + 0x7fffu + ((v.u >> 16) & 1u);
    return (unsigned short)(r >> 16);
}
__device__ __forceinline__ float bf2f(unsigned short u) {
    union { unsigned u; float f; } v; v.u = ((unsigned)u) << 16;
    return v.f;
}

// ---------------- in-block split-K MFMA GEMM, 32x64 tile (R10-measured ~17us better than 64x64) ----
// 512 threads: K-groups g=0/1 (384 each), 4 waves/group, wave tile 32x16 (2 MFMA/step).
// Register-prefetch double-buffered LDS, one barrier per K-step; g1 dumps partial to LDS, g0 adds+stores.
__device__ __forceinline__ void gemm_inblk_splitk(
    const float* __restrict__ A, const float* __restrict__ W,
    float* __restrict__ out, int row0, int n0, int outcol0, int ldw, int outld)
{
    __shared__ unsigned short Al[2][2][32][40];
    __shared__ unsigned short Bl[2][2][64][40];
    __shared__ float red[32][65];
    const int tid = threadIdx.x;
    const int g = tid >> 8;
    const int t = tid & 255;
    const int lane = t & 63, w4 = t >> 6;
    const int quad = lane >> 4, lr = lane & 15;
    const int k0base = g * 384;

    f32x4 acc[2] = {{0.f,0.f,0.f,0.f},{0.f,0.f,0.f,0.f}};

    float4 ra, rb[2];
    {
        ra = *(const float4*)&A[(size_t)(row0 + (t >> 3)) * 768 + k0base + (t & 7) * 4];
        #pragma unroll
        for (int l = 0; l < 2; ++l) {
            int idy = t + l * 256;
            rb[l] = *(const float4*)&W[(size_t)(k0base + (idy >> 4)) * ldw + n0 + (idy & 15) * 4];
        }
    }
    {
        *(ushort4*)&Al[g][0][t >> 3][(t & 7) * 4] =
            make_ushort4(f2bf(ra.x), f2bf(ra.y), f2bf(ra.z), f2bf(ra.w));
        #pragma unroll
        for (int l = 0; l < 2; ++l) {
            int idy = t + l * 256;
            int kr = idy >> 4, nq = (idy & 15) * 4;
            int col = (((kr >> 3) ^ ((idy & 15) >> 2)) << 3) | (kr & 7);
            Bl[g][0][nq + 0][col] = f2bf(rb[l].x);
            Bl[g][0][nq + 1][col] = f2bf(rb[l].y);
            Bl[g][0][nq + 2][col] = f2bf(rb[l].z);
            Bl[g][0][nq + 3][col] = f2bf(rb[l].w);
        }
    }
    __syncthreads();

    const int ITER = 12;   // 384 / 32
    #pragma unroll
    for (int i = 0; i < ITER; ++i) {
        const int cur = i & 1, nxt = cur ^ 1;
        float4 na, nb[2];
        if (i + 1 < ITER) {
            int kn = k0base + (i + 1) * 32;
            na = *(const float4*)&A[(size_t)(row0 + (t >> 3)) * 768 + kn + (t & 7) * 4];
            #pragma unroll
            for (int l = 0; l < 2; ++l) {
                int idy = t + l * 256;
                nb[l] = *(const float4*)&W[(size_t)(kn + (idy >> 4)) * ldw + n0 + (idy & 15) * 4];
            }
        }
        short8 af[2], bfr;
        af[0] = *(const short8*)&Al[g][cur][lr][quad << 3];
        af[1] = *(const short8*)&Al[g][cur][16 + lr][quad << 3];
        {
            int csw = quad ^ (w4 & 3);
            bfr = *(const short8*)&Bl[g][cur][w4 * 16 + lr][csw << 3];
        }
        acc[0] = __builtin_amdgcn_mfma_f32_16x16x32_bf16(af[0], bfr, acc[0], 0, 0, 0);
        acc[1] = __builtin_amdgcn_mfma_f32_16x16x32_bf16(af[1], bfr, acc[1], 0, 0, 0);
        if (i + 1 < ITER) {
            *(ushort4*)&Al[g][nxt][t >> 3][(t & 7) * 4] =
                make_ushort4(f2bf(na.x), f2bf(na.y), f2bf(na.z), f2bf(na.w));
            #pragma unroll
            for (int l = 0; l < 2; ++l) {
                int idy = t + l * 256;
                int kr = idy >> 4, nq = (idy & 15) * 4;
                int col = (((kr >> 3) ^ ((idy & 15) >> 2)) << 3) | (kr & 7);
                Bl[g][nxt][nq + 0][col] = f2bf(nb[l].x);
                Bl[g][nxt][nq + 1][col] = f2bf(nb[l].y);
                Bl[g][nxt][nq + 2][col] = f2bf(nb[l].z);
                Bl[g][nxt][nq + 3][col] = f2bf(nb[l].w);
            }
        }
        __syncthreads();
    }
    if (g == 1) {
        #pragma unroll
        for (int mi = 0; mi < 2; ++mi)
            #pragma unroll
            for (int r = 0; r < 4; ++r)
                red[mi * 16 + quad * 4 + r][w4 * 16 + lr] = acc[mi][r];
    }
    __syncthreads();
    if (g == 0) {
        #pragma unroll
        for (int mi = 0; mi < 2; ++mi)
            #pragma unroll
            for (int r = 0; r < 4; ++r) {
                int rr = mi * 16 + quad * 4 + r;
                out[(size_t)(row0 + rr) * outld + outcol0 + w4 * 16 + lr] =
                    acc[mi][r] + red[rr][w4 * 16 + lr];
            }
    }
}

// qkv: hidden(1024x768) @ [Wq|Wk|Wv] -> qkv(1024x1152). grid (18,32) x 512
__global__ __launch_bounds__(512) void gemm_qkv_mfma(
    const float* __restrict__ H, const float* __restrict__ Wq,
    const float* __restrict__ Wk, const float* __restrict__ Wv,
    float* __restrict__ out)
{
    const int nt = blockIdx.x, mt = blockIdx.y;
    const float* W; int ldw, n0;
    if (nt < 3)      { W = Wq; ldw = 192; n0 = nt * 64; }
    else if (nt < 6) { W = Wk; ldw = 192; n0 = (nt - 3) * 64; }
    else             { W = Wv; ldw = 768; n0 = (nt - 6) * 64; }
    gemm_inblk_splitk(H, W, out, mt * 32, n0, nt * 64, ldw, 1152);
}

// wo: y(1024x768) @ Wo(768x768) -> out(1024x768). grid (12,32) x 512
__global__ __launch_bounds__(512) void gemm_wo_mfma(
    const float* __restrict__ Y, const float* __restrict__ Wo, float* __restrict__ out)
{
    const int nt = blockIdx.x, mt = blockIdx.y;
    gemm_inblk_splitk(Y, Wo, out, mt * 32, nt * 64, nt * 64, 768, 768);
}

// ---------------- per-chunk state via MFMA -> S_T bf16 ----------------
// S_T[h][c][d][n] (ld=288, bf16): A = [V^T|ones] (m=80pad, row 64 = ones for z), B = phiK (n=320pad).
// grid (16, 12) x 256.
__global__ __launch_bounds__(256) void chunk_state_k(
    const float* __restrict__ qkv, unsigned short* __restrict__ St, float* __restrict__ z)
{
    const int c = blockIdx.x, h = blockIdx.y;
    __shared__ float Kc[64][17];
    __shared__ unsigned short Pk[320][72];
    __shared__ unsigned short Vt[80][72];
    const int tid = threadIdx.x;
    const int lane = tid & 63, wave = tid >> 6;
    const int quad = lane >> 4, lr = lane & 15;

    {
        int s = tid >> 2, f4 = (tid & 3) * 4;
        float4 kv = *(const float4*)&qkv[(size_t)(c * 64 + s) * 1152 + 192 + h * 16 + f4];
        Kc[s][f4 + 0] = kv.x; Kc[s][f4 + 1] = kv.y; Kc[s][f4 + 2] = kv.z; Kc[s][f4 + 3] = kv.w;
    }
    #pragma unroll
    for (int l = 0; l < 4; ++l) {
        int idx = tid + l * 256;
        int s = idx >> 4, d4 = (idx & 15) * 4;
        float4 vv = *(const float4*)&qkv[(size_t)(c * 64 + s) * 1152 + 384 + h * 64 + d4];
        Vt[d4 + 0][s] = f2bf(vv.x);
        Vt[d4 + 1][s] = f2bf(vv.y);
        Vt[d4 + 2][s] = f2bf(vv.z);
        Vt[d4 + 3][s] = f2bf(vv.w);
    }
    for (int idx = tid; idx < 16 * 72; idx += 256) {
        int rr = 64 + idx / 72, ss = idx % 72;
        Vt[rr][ss] = (rr == 64 && ss < 64) ? (unsigned short)0x3F80 : (unsigned short)0;
    }
    __syncthreads();
    for (int idx = tid; idx < 2880; idx += 256) {
        int n = idx / 9, s8 = (idx % 9) * 8;
        short8 v8;
        #pragma unroll
        for (int tt = 0; tt < 8; ++tt) {
            int s = s8 + tt;
            float ph = 0.f;
            if (s < 64 && n < 273) {
                if (n == 0) ph = 1.f;
                else if (n < 17) ph = Kc[s][n - 1] * 0.5f;
                else { int m = n - 17; ph = Kc[s][m >> 4] * Kc[s][m & 15] * C2; }
            }
            v8[tt] = (short)f2bf(ph);
        }
        *(short8*)&Pk[n][s8] = v8;
    }
    __syncthreads();

    f32x4 acc[5][5];
    #pragma unroll
    for (int a = 0; a < 5; ++a)
        #pragma unroll
        for (int b = 0; b < 5; ++b) acc[a][b] = (f32x4){0.f, 0.f, 0.f, 0.f};
    #pragma unroll
    for (int ks = 0; ks < 2; ++ks) {
        short8 af[5], bfr[5];
        #pragma unroll
        for (int mt = 0; mt < 5; ++mt)
            af[mt] = *(const short8*)&Vt[mt * 16 + lr][ks * 32 + quad * 8];
        #pragma unroll
        for (int nt = 0; nt < 5; ++nt)
            bfr[nt] = *(const short8*)&Pk[(wave * 5 + nt) * 16 + lr][ks * 32 + quad * 8];
        #pragma unroll
        for (int mt = 0; mt < 5; ++mt)
            #pragma unroll
            for (int nt = 0; nt < 5; ++nt)
                acc[mt][nt] = __builtin_amdgcn_mfma_f32_16x16x32_bf16(af[mt], bfr[nt], acc[mt][nt], 0, 0, 0);
    }
    unsigned short* Sbt = St + (size_t)(h * 16 + c) * 18432;
    float* zb = z + (size_t)(h * 16 + c) * 273;
    #pragma unroll
    for (int nt = 0; nt < 5; ++nt) {
        int n = (wave * 5 + nt) * 16 + lr;
        if (n < 273) {
            #pragma unroll
            for (int mt = 0; mt < 4; ++mt)
                #pragma unroll
                for (int r = 0; r < 4; ++r)
                    Sbt[(mt * 16 + quad * 4 + r) * 288 + n] = f2bf(acc[mt][nt][r]);
            if (quad == 0) zb[n] = acc[4][nt][0];   // d==64 ones-row -> z
        }
    }
}

// ---------------- exclusive prefix over 16 chunks (in place; S bf16, z fp32) ----------------
__global__ __launch_bounds__(256) void scan_state_k(unsigned short* __restrict__ St, float* __restrict__ z)
{
    const int NS = 12 * 64 * 273;   // 209,664
    int e = blockIdx.x * 256 + threadIdx.x;
    if (e < NS) {
        int hh = e / (64 * 273), rem = e % (64 * 273);
        int d = rem / 273, n = rem % 273;
        unsigned short* p = St + (size_t)hh * 16 * 18432 + d * 288 + n;
        float run = 0.f;
        #pragma unroll
        for (int c = 0; c < 16; ++c) {
            float v = bf2f(p[c * 18432]);
            p[c * 18432] = f2bf(run);
            run += v;
        }
    } else if (e < NS + 12 * 273) {
        int e2 = e - NS, hh = e2 / 273, n = e2 % 273;
        float* p = z + hh * 16 * 273 + n;
        float run = 0.f;
        #pragma unroll
        for (int c = 0; c < 16; ++c) { float v = p[c * 273]; p[c * 273] = run; run += v; }
    }
}

// ---------------- per-chunk output via ONE fused MFMA GEMM (reads pre-scanned states) ----------------
__global__ __launch_bounds__(256) void chunk_out_k(
    const float* __restrict__ qkv, const unsigned short* __restrict__ St, const float* __restrict__ z,
    float* __restrict__ y)
{
    const int c = blockIdx.x, h = blockIdx.y;
    __shared__ float Qc[64][17];
    __shared__ unsigned short Aq[64][40];
    __shared__ unsigned short Kb[64][40];
    __shared__ unsigned short Pq[64][360];
    __shared__ unsigned short Sv[64][360];
    __shared__ float zl[288];
    __shared__ float dpart[6][64];
    const int tid = threadIdx.x;
    const int lane = tid & 63, wave = tid >> 6;
    const int wm = wave & 1, wn = wave >> 1;
    const int quad = lane >> 4, lr = lane & 15;

    {
        int s = tid >> 2, f4 = (tid & 3) * 4;
        const float* base = &qkv[(size_t)(c * 64 + s) * 1152 + h * 16];
        float4 qv = *(const float4*)&base[f4];
        float4 kv = *(const float4*)&base[192 + f4];
        Qc[s][f4 + 0] = qv.x; Qc[s][f4 + 1] = qv.y; Qc[s][f4 + 2] = qv.z; Qc[s][f4 + 3] = qv.w;
        *(ushort4*)&Aq[s][f4] = make_ushort4(f2bf(qv.x), f2bf(qv.y), f2bf(qv.z), f2bf(qv.w));
        *(ushort4*)&Kb[s][f4] = make_ushort4(f2bf(kv.x), f2bf(kv.y), f2bf(kv.z), f2bf(kv.w));
        *(ushort4*)&Aq[s][16 + (tid & 3) * 4] = make_ushort4(0, 0, 0, 0);
        *(ushort4*)&Kb[s][16 + (tid & 3) * 4] = make_ushort4(0, 0, 0, 0);
    }
    #pragma unroll
    for (int l = 0; l < 4; ++l) {                    // V -> Sv cols 288..351
        int idx = tid + l * 256;
        int s = idx >> 4, d4 = (idx & 15) * 4;
        float4 vv = *(const float4*)&qkv[(size_t)(c * 64 + s) * 1152 + 384 + h * 64 + d4];
        Sv[d4 + 0][288 + s] = f2bf(vv.x);
        Sv[d4 + 1][288 + s] = f2bf(vv.y);
        Sv[d4 + 2][288 + s] = f2bf(vv.z);
        Sv[d4 + 3][288 + s] = f2bf(vv.w);
    }
    // S_T (bf16) rows -> Sv cols 0..272 via straight vector copies
    const unsigned short* Sgt = St + (size_t)(h * 16 + c) * 18432;
    for (int idx = tid; idx < 64 * 34; idx += 256) {       // n 0..271
        int d = idx / 34, n8 = (idx % 34) * 8;
        *(ushort8*)&Sv[d][n8] = *(const ushort8*)&Sgt[d * 288 + n8];
    }
    for (int idx = tid; idx < 64; idx += 256) Sv[idx][272] = Sgt[idx * 288 + 272];
    for (int idx = tid; idx < 64 * 15; idx += 256) {       // zero n 273..287
        int d = idx / 15, n = 273 + idx % 15;
        Sv[d][n] = 0;
    }
    const float* zg = z + (size_t)(h * 16 + c) * 273;
    for (int idx = tid; idx < 288; idx += 256) zl[idx] = (idx < 273) ? zg[idx] : 0.f;
    __syncthreads();

    f32x4 accS[2][2] = {{{0.f,0.f,0.f,0.f},{0.f,0.f,0.f,0.f}},
                        {{0.f,0.f,0.f,0.f},{0.f,0.f,0.f,0.f}}};
    {
        short8 af[2], bfr[2];
        #pragma unroll
        for (int mi = 0; mi < 2; ++mi)
            af[mi] = *(const short8*)&Aq[wm * 32 + mi * 16 + lr][quad * 8];
        #pragma unroll
        for (int ni = 0; ni < 2; ++ni)
            bfr[ni] = *(const short8*)&Kb[wn * 32 + ni * 16 + lr][quad * 8];
        #pragma unroll
        for (int mi = 0; mi < 2; ++mi)
            #pragma unroll
            for (int ni = 0; ni < 2; ++ni)
                accS[mi][ni] = __builtin_amdgcn_mfma_f32_16x16x32_bf16(af[mi], bfr[ni], accS[mi][ni], 0, 0, 0);
    }

    {
        int i = lane;
        float qr[16];
        #pragma unroll
        for (int f = 0; f < 16; ++f) qr[f] = Qc[i][f];
        float dp = 0.f;
        int n0 = wave * 72;
        for (int n = n0; n < n0 + 72; ++n) {
            float ph;
            if (n == 0) ph = 1.f;
            else if (n < 17) ph = qr[n - 1] * 0.5f;
            else if (n < 273) { int m = n - 17; ph = qr[m >> 4] * qr[m & 15] * C2; }
            else ph = 0.f;
            Pq[i][n] = f2bf(ph);
            dp += ph * zl[n];
        }
        dpart[wave][i] = dp;
    }

    #pragma unroll
    for (int mi = 0; mi < 2; ++mi) {
        float rs[4] = {0.f, 0.f, 0.f, 0.f};
        #pragma unroll
        for (int ni = 0; ni < 2; ++ni)
            #pragma unroll
            for (int r = 0; r < 4; ++r) {
                int i = wm * 32 + mi * 16 + quad * 4 + r;
                int j = wn * 32 + ni * 16 + lr;
                float u = accS[mi][ni][r];
                float sc = (j <= i) ? (1.f + 0.25f * u + u * u * (1.f / 32.f)) : 0.f;
                rs[r] += sc;
                Pq[i][288 + j] = f2bf(sc);
            }
        #pragma unroll
        for (int r = 0; r < 4; ++r) {
            float v = rs[r];
            v += __shfl_xor(v, 1);
            v += __shfl_xor(v, 2);
            v += __shfl_xor(v, 4);
            v += __shfl_xor(v, 8);
            if (lr == 0) dpart[4 + wn][wm * 32 + mi * 16 + quad * 4 + r] = v;
        }
    }
    __syncthreads();

    f32x4 acc[2][2] = {{{0.f,0.f,0.f,0.f},{0.f,0.f,0.f,0.f}},
                       {{0.f,0.f,0.f,0.f},{0.f,0.f,0.f,0.f}}};
    #pragma unroll
    for (int ks = 0; ks < 11; ++ks) {
        short8 af[2], bfr[2];
        #pragma unroll
        for (int mi = 0; mi < 2; ++mi)
            af[mi] = *(const short8*)&Pq[wm * 32 + mi * 16 + lr][ks * 32 + quad * 8];
        #pragma unroll
        for (int ni = 0; ni < 2; ++ni)
            bfr[ni] = *(const short8*)&Sv[wn * 32 + ni * 16 + lr][ks * 32 + quad * 8];
        #pragma unroll
        for (int mi = 0; mi < 2; ++mi)
            #pragma unroll
            for (int ni = 0; ni < 2; ++ni)
                acc[mi][ni] = __builtin_amdgcn_mfma_f32_16x16x32_bf16(af[mi], bfr[ni], acc[mi][ni], 0, 0, 0);
    }

    #pragma unroll
    for (int mi = 0; mi < 2; ++mi)
        #pragma unroll
        for (int r = 0; r < 4; ++r) {
            int i = wm * 32 + mi * 16 + quad * 4 + r;
            float den = dpart[0][i] + dpart[1][i] + dpart[2][i] +
                        dpart[3][i] + dpart[4][i] + dpart[5][i] + 1e-12f;
            float rden = 1.f / den;
            #pragma unroll
            for (int ni = 0; ni < 2; ++ni)
                y[(size_t)(c * 64 + i) * 768 + h * 64 + wn * 32 + ni * 16 + lr] = acc[mi][ni][r] * rden;
        }
}

extern "C" void kernel_launch(void* const* d_in, const int* in_sizes, int n_in,
                              void* d_out, int out_size, void* d_ws, size_t ws_size,
                              hipStream_t stream) {
    const float* hs = (const float*)d_in[0];
    const float* Wq = (const float*)d_in[1];
    const float* Wk = (const float*)d_in[2];
    const float* Wv = (const float*)d_in[3];
    const float* Wo = (const float*)d_in[4];
    float* out = (float*)d_out;
    float* ws  = (float*)d_ws;

    float* qkv = ws;                                        // 1024*1152 fp32
    float* yb  = ws + 1179648;                              // 1024*768 fp32
    unsigned short* St = (unsigned short*)(ws + 1966080);   // 192 x 64 x 288 bf16
    float* zb  = ws + 5320704;                              // 192 x 273 fp32

    gemm_qkv_mfma<<<dim3(18, 32), 512, 0, stream>>>(hs, Wq, Wk, Wv, qkv);
    chunk_state_k<<<dim3(16, 12), 256, 0, stream>>>(qkv, St, zb);
    scan_state_k <<<832, 256, 0, stream>>>(St, zb);
    chunk_out_k  <<<dim3(16, 12), 256, 0, stream>>>(qkv, St, zb, yb);
    gemm_wo_mfma <<<dim3(12, 32), 512, 0, stream>>>(yb, Wo, out);
}